// Round 5
// baseline (265.152 us; speedup 1.0000x reference)
//
#include <hip/hip_runtime.h>
#include <cstdint>
#include <cstddef>

#define KTOP 10
#define BQ 4096
#define BD 32768
#define THREADS 256
#define F4_PER_ROW (BD / 4)            // 8192
#define ITERS (F4_PER_ROW / THREADS)   // 32
#define CAP 512                        // candidate slots (expected ~44/row); overflow -> exact fallback
#define T_STATIC 3.0f

typedef float nf4 __attribute__((ext_vector_type(4)));   // native vec4 for nontemporal builtin

// Tie-aware sorted top-10 register ladder insert (ties -> lower index, matches lax.top_k).
__device__ __forceinline__ void insert_tie(float v, int j, float (&tv)[KTOP], int (&ti)[KTOP]) {
    const bool enter = (v > tv[KTOP - 1]) || (v == tv[KTOP - 1] && j < ti[KTOP - 1]);
    if (enter) {
        bool cc[KTOP];
#pragma unroll
        for (int k = 0; k < KTOP; ++k) cc[k] = (v > tv[k]) || (v == tv[k] && j < ti[k]);
#pragma unroll
        for (int k = KTOP - 1; k >= 1; --k) {
            tv[k] = cc[k] ? (cc[k - 1] ? tv[k - 1] : v) : tv[k];
            ti[k] = cc[k] ? (cc[k - 1] ? ti[k - 1] : j) : ti[k];
        }
        if (cc[0]) { tv[0] = v; ti[0] = j; }
    }
}

// 10 wave-argmax extraction rounds over 64 lane-local ladders; no barriers.
// Lane r (r<10) receives rank-r (value,index) in (myv,myi). Pop via static shift (no
// runtime register indexing -> stays in VGPRs). Tie-break: lower doc index.
__device__ __forceinline__ void wave_extract10(float (&tv)[KTOP], int (&ti)[KTOP],
                                               int lane, float &myv, int &myi) {
#pragma unroll
    for (int r = 0; r < KTOP; ++r) {
        float bv = tv[0]; int bi = ti[0]; int bl = lane;
#pragma unroll
        for (int m = 32; m >= 1; m >>= 1) {
            const float ov = __shfl_xor(bv, m);
            const int   oi = __shfl_xor(bi, m);
            const int   ol = __shfl_xor(bl, m);
            const bool take = (ov > bv) || (ov == bv && oi < bi);
            bv = take ? ov : bv;
            bi = take ? oi : bi;
            bl = take ? ol : bl;
        }
        if (lane == bl) {                       // winner pops its list head (static shift)
#pragma unroll
            for (int k = 0; k < KTOP - 1; ++k) { tv[k] = tv[k + 1]; ti[k] = ti[k + 1]; }
            tv[KTOP - 1] = -INFINITY; ti[KTOP - 1] = 0x7fffffff;
        }
        if (lane == r) { myv = bv; myi = bi; }
    }
}

__global__ __launch_bounds__(THREADS) void topk_ndcg_rows(
    const float* __restrict__ scores,
    const int* __restrict__ mask,          // jnp.bool_ arrives as int32 on device
    float* __restrict__ per_row)
{
    const int row  = blockIdx.x;
    const int tid  = threadIdx.x;
    const int lane = tid & 63;
    const int wv   = tid >> 6;
    const nf4* row4 = reinterpret_cast<const nf4*>(scores + (size_t)row * BD);

    __shared__ int   s_cnt;
    __shared__ float cv[CAP];              // candidates; reused by fallback (40 entries)
    __shared__ int   ci[CAP];

    if (tid == 0) s_cnt = 0;
    __syncthreads();

    // ---- Pass 1: stream the row with 4-deep batched nontemporal loads ----
    for (int i = 0; i < ITERS; i += 4) {
        nf4 xs[4];
#pragma unroll
        for (int u = 0; u < 4; ++u)
            xs[u] = __builtin_nontemporal_load(row4 + (i + u) * THREADS + tid);
#pragma unroll
        for (int u = 0; u < 4; ++u) {
            const nf4 x = xs[u];
            const float m = fmaxf(fmaxf(x.x, x.y), fmaxf(x.z, x.w));
            if (m >= T_STATIC) {
                const int jb = ((i + u) * THREADS + tid) * 4;
                const float vs[4] = { x.x, x.y, x.z, x.w };
#pragma unroll
                for (int c = 0; c < 4; ++c) {
                    if (vs[c] >= T_STATIC) {
                        const int p = atomicAdd(&s_cnt, 1);
                        if (p < CAP) { cv[p] = vs[c]; ci[p] = jb + c; }
                    }
                }
            }
        }
    }
    __syncthreads();
    int n = s_cnt;                          // uniform across block

    float tv[KTOP]; int ti[KTOP];
#pragma unroll
    for (int k = 0; k < KTOP; ++k) { tv[k] = -INFINITY; ti[k] = 0x7fffffff; }

    if (n < KTOP || n > CAP) {
        // ---- Exact fallback for ANY input: per-thread ladder over full row ----
        for (int i = 0; i < ITERS; ++i) {
            const int f4 = i * THREADS + tid;
            const nf4 x = row4[f4];
            const int jb = f4 * 4;
            const float vs[4] = { x.x, x.y, x.z, x.w };
#pragma unroll
            for (int c = 0; c < 4; ++c) insert_tie(vs[c], jb + c, tv, ti);
        }
        // Wave-local top-10 (block top-10 is a subset of the union of wave top-10s).
        float fv = 0.0f; int fi = 0;
        wave_extract10(tv, ti, lane, fv, fi);
        if (lane < KTOP) { cv[wv * KTOP + lane] = fv; ci[wv * KTOP + lane] = fi; }
        __syncthreads();
        n = 4 * KTOP;
    }

    // ---- Wave 0: exact tie-aware top-10 over n candidates, then the loss ----
    if (wv == 0) {
#pragma unroll
        for (int k = 0; k < KTOP; ++k) { tv[k] = -INFINITY; ti[k] = 0x7fffffff; }
        for (int p = lane; p < n; p += 64) insert_tie(cv[p], ci[p], tv, ti);

        float myv = 0.0f; int myi = 0;
        wave_extract10(tv, ti, lane, myv, myi);

        const int* mrow = mask + (size_t)row * BD;
        const int pos = (lane < KTOP) ? ((mrow[myi] != 0) ? 1 : 0) : 0;

        int cnt = pos;                      // number of positives among top-10
#pragma unroll
        for (int m = 32; m >= 1; m >>= 1) cnt += __shfl_xor(cnt, m);

        const float invd = 1.0f / log2f((float)(lane + 2));   // 1/log2(rank+1), rank=lane+1
        float a = pos ? invd : 0.0f;                          // actual DCG term
        float b = (lane < cnt) ? invd : 0.0f;                 // ideal DCG term
#pragma unroll
        for (int m = 32; m >= 1; m >>= 1) {
            a += __shfl_xor(a, m);
            b += __shfl_xor(b, m);
        }
        if (lane == 0) per_row[row] = (b > 0.0f) ? (1.0f - a / b) : 0.0f;
    }
}

// Deterministic reduction of the 4096 per-row losses -> scalar mean.
__global__ __launch_bounds__(256) void reduce_mean(
    const float* __restrict__ per_row, float* __restrict__ out)
{
    const int tid = threadIdx.x;
    float s = 0.0f;
    for (int i = tid; i < BQ; i += 256) s += per_row[i];
#pragma unroll
    for (int m = 32; m >= 1; m >>= 1) s += __shfl_xor(s, m);
    __shared__ float ws[4];
    if ((tid & 63) == 0) ws[tid >> 6] = s;
    __syncthreads();
    if (tid == 0) out[0] = (ws[0] + ws[1] + ws[2] + ws[3]) / (float)BQ;
}

extern "C" void kernel_launch(void* const* d_in, const int* in_sizes, int n_in,
                              void* d_out, int out_size, void* d_ws, size_t ws_size,
                              hipStream_t stream) {
    const float* scores = (const float*)d_in[0];
    const int*   mask   = (const int*)d_in[1];     // bool_ -> int32 on device
    float* per_row = (float*)d_ws;                 // 4096 floats, rewritten every call

    topk_ndcg_rows<<<BQ, THREADS, 0, stream>>>(scores, mask, per_row);
    reduce_mean<<<1, 256, 0, stream>>>(per_row, (float*)d_out);
}

// Round 6
// 210.912 us; speedup vs baseline: 1.2572x; 1.2572x over previous
//
#include <hip/hip_runtime.h>
#include <cstdint>
#include <cstddef>

#define KTOP 10
#define BQ 4096
#define BD 32768
#define THREADS 256
#define F4_PER_ROW (BD / 4)            // 8192
#define ITERS (F4_PER_ROW / THREADS)   // 32
#define BATCH 4
#define CAP 512                        // candidate slots (expected ~44/row); overflow -> exact fallback
#define T_STATIC 3.0f

typedef float nf4 __attribute__((ext_vector_type(4)));

// Tie-aware sorted top-10 register ladder insert (ties -> lower index, matches lax.top_k).
__device__ __forceinline__ void insert_tie(float v, int j, float (&tv)[KTOP], int (&ti)[KTOP]) {
    const bool enter = (v > tv[KTOP - 1]) || (v == tv[KTOP - 1] && j < ti[KTOP - 1]);
    if (enter) {
        bool cc[KTOP];
#pragma unroll
        for (int k = 0; k < KTOP; ++k) cc[k] = (v > tv[k]) || (v == tv[k] && j < ti[k]);
#pragma unroll
        for (int k = KTOP - 1; k >= 1; --k) {
            tv[k] = cc[k] ? (cc[k - 1] ? tv[k - 1] : v) : tv[k];
            ti[k] = cc[k] ? (cc[k - 1] ? ti[k - 1] : j) : ti[k];
        }
        if (cc[0]) { tv[0] = v; ti[0] = j; }
    }
}

// 10 wave-argmax extraction rounds over 64 lane-local ladders; no barriers.
// Lane r (r<10) receives rank-r (value,index) in (myv,myi). Pop via static shift.
__device__ __forceinline__ void wave_extract10(float (&tv)[KTOP], int (&ti)[KTOP],
                                               int lane, float &myv, int &myi) {
#pragma unroll
    for (int r = 0; r < KTOP; ++r) {
        float bv = tv[0]; int bi = ti[0]; int bl = lane;
#pragma unroll
        for (int m = 32; m >= 1; m >>= 1) {
            const float ov = __shfl_xor(bv, m);
            const int   oi = __shfl_xor(bi, m);
            const int   ol = __shfl_xor(bl, m);
            const bool take = (ov > bv) || (ov == bv && oi < bi);
            bv = take ? ov : bv;
            bi = take ? oi : bi;
            bl = take ? ol : bl;
        }
        if (lane == bl) {                       // winner pops its list head (static shift)
#pragma unroll
            for (int k = 0; k < KTOP - 1; ++k) { tv[k] = tv[k + 1]; ti[k] = ti[k + 1]; }
            tv[KTOP - 1] = -INFINITY; ti[KTOP - 1] = 0x7fffffff;
        }
        if (lane == r) { myv = bv; myi = bi; }
    }
}

__global__ __launch_bounds__(THREADS) void topk_ndcg_rows(
    const float* __restrict__ scores,
    const int* __restrict__ mask,          // jnp.bool_ arrives as int32 on device
    float* __restrict__ per_row)
{
    const int row  = blockIdx.x;
    const int tid  = threadIdx.x;
    const int lane = tid & 63;
    const int wv   = tid >> 6;
    const nf4* row4 = reinterpret_cast<const nf4*>(scores + (size_t)row * BD);

    __shared__ int   s_cnt;
    __shared__ float cv[CAP];              // candidates; reused by fallback (40 entries)
    __shared__ int   ci[CAP];

    if (tid == 0) s_cnt = 0;
    __syncthreads();

    // ---- Pass 1: stream with explicit 4-deep prefetch double-buffer (plain cached loads) ----
    nf4 cur[BATCH];
#pragma unroll
    for (int u = 0; u < BATCH; ++u) cur[u] = row4[u * THREADS + tid];

    for (int i = 0; i < ITERS; i += BATCH) {
        nf4 nxt[BATCH];
        if (i + BATCH < ITERS) {
#pragma unroll
            for (int u = 0; u < BATCH; ++u)
                nxt[u] = row4[(i + BATCH + u) * THREADS + tid];   // issued before filtering cur
        }
#pragma unroll
        for (int u = 0; u < BATCH; ++u) {
            const nf4 x = cur[u];
            const float m = fmaxf(fmaxf(x.x, x.y), fmaxf(x.z, x.w));
            if (m >= T_STATIC) {
                const int jb = ((i + u) * THREADS + tid) * 4;
                const float vs[4] = { x.x, x.y, x.z, x.w };
#pragma unroll
                for (int c = 0; c < 4; ++c) {
                    if (vs[c] >= T_STATIC) {
                        const int p = atomicAdd(&s_cnt, 1);
                        if (p < CAP) { cv[p] = vs[c]; ci[p] = jb + c; }
                    }
                }
            }
        }
        if (i + BATCH < ITERS) {
#pragma unroll
            for (int u = 0; u < BATCH; ++u) cur[u] = nxt[u];
        }
    }
    __syncthreads();
    int n = s_cnt;                          // uniform across block

    float tv[KTOP]; int ti[KTOP];
#pragma unroll
    for (int k = 0; k < KTOP; ++k) { tv[k] = -INFINITY; ti[k] = 0x7fffffff; }

    if (n < KTOP || n > CAP) {
        // ---- Exact fallback for ANY input: per-thread ladder over full row ----
        for (int i = 0; i < ITERS; ++i) {
            const int f4 = i * THREADS + tid;
            const nf4 x = row4[f4];
            const int jb = f4 * 4;
            const float vs[4] = { x.x, x.y, x.z, x.w };
#pragma unroll
            for (int c = 0; c < 4; ++c) insert_tie(vs[c], jb + c, tv, ti);
        }
        // Wave-local top-10 (block top-10 is a subset of the union of wave top-10s).
        float fv = 0.0f; int fi = 0;
        wave_extract10(tv, ti, lane, fv, fi);
        if (lane < KTOP) { cv[wv * KTOP + lane] = fv; ci[wv * KTOP + lane] = fi; }
        __syncthreads();
        n = 4 * KTOP;
    }

    // ---- Wave 0: exact tie-aware top-10 over n candidates, then the loss ----
    if (wv == 0) {
#pragma unroll
        for (int k = 0; k < KTOP; ++k) { tv[k] = -INFINITY; ti[k] = 0x7fffffff; }
        for (int p = lane; p < n; p += 64) insert_tie(cv[p], ci[p], tv, ti);

        float myv = 0.0f; int myi = 0;
        wave_extract10(tv, ti, lane, myv, myi);

        const int* mrow = mask + (size_t)row * BD;
        const int pos = (lane < KTOP) ? ((mrow[myi] != 0) ? 1 : 0) : 0;

        int cnt = pos;                      // number of positives among top-10
#pragma unroll
        for (int m = 32; m >= 1; m >>= 1) cnt += __shfl_xor(cnt, m);

        const float invd = 1.0f / log2f((float)(lane + 2));   // 1/log2(rank+1), rank=lane+1
        float a = pos ? invd : 0.0f;                          // actual DCG term
        float b = (lane < cnt) ? invd : 0.0f;                 // ideal DCG term
#pragma unroll
        for (int m = 32; m >= 1; m >>= 1) {
            a += __shfl_xor(a, m);
            b += __shfl_xor(b, m);
        }
        if (lane == 0) per_row[row] = (b > 0.0f) ? (1.0f - a / b) : 0.0f;
    }
}

// Deterministic reduction of the 4096 per-row losses -> scalar mean.
__global__ __launch_bounds__(256) void reduce_mean(
    const float* __restrict__ per_row, float* __restrict__ out)
{
    const int tid = threadIdx.x;
    float s = 0.0f;
    for (int i = tid; i < BQ; i += 256) s += per_row[i];
#pragma unroll
    for (int m = 32; m >= 1; m >>= 1) s += __shfl_xor(s, m);
    __shared__ float ws[4];
    if ((tid & 63) == 0) ws[tid >> 6] = s;
    __syncthreads();
    if (tid == 0) out[0] = (ws[0] + ws[1] + ws[2] + ws[3]) / (float)BQ;
}

extern "C" void kernel_launch(void* const* d_in, const int* in_sizes, int n_in,
                              void* d_out, int out_size, void* d_ws, size_t ws_size,
                              hipStream_t stream) {
    const float* scores = (const float*)d_in[0];
    const int*   mask   = (const int*)d_in[1];     // bool_ -> int32 on device
    float* per_row = (float*)d_ws;                 // 4096 floats, rewritten every call

    topk_ndcg_rows<<<BQ, THREADS, 0, stream>>>(scores, mask, per_row);
    reduce_mean<<<1, 256, 0, stream>>>(per_row, (float*)d_out);
}

// Round 7
// 135.742 us; speedup vs baseline: 1.9534x; 1.5538x over previous
//
#include <hip/hip_runtime.h>
#include <cstdint>
#include <cstddef>

#define KTOP 10
#define BQ 4096
#define BD 32768
#define THREADS 256
#define F4_PER_ROW (BD / 4)            // 8192
#define ITERS (F4_PER_ROW / THREADS)   // 32
#define CAPL 512                       // LDS collection slots (expected ~44/row)
#define CAPG 256                       // global candidate slots per row
#define T_STATIC 3.0f
#define CAP_FUSED 2560                 // fused-fallback (round-3) LDS cap

// ws layout: [0,16KB) per_row float[BQ]; [16KB,32KB) counts int[BQ];
//            [32KB, +4MB) gval float[BQ*CAPG]; then gidx int[BQ*CAPG].
#define WS_REQ (32768 + (size_t)BQ * CAPG * 8)

// Tie-aware sorted top-10 register ladder insert (ties -> lower index, matches lax.top_k).
__device__ __forceinline__ void insert_tie(float v, int j, float (&tv)[KTOP], int (&ti)[KTOP]) {
    const bool enter = (v > tv[KTOP - 1]) || (v == tv[KTOP - 1] && j < ti[KTOP - 1]);
    if (enter) {
        bool cc[KTOP];
#pragma unroll
        for (int k = 0; k < KTOP; ++k) cc[k] = (v > tv[k]) || (v == tv[k] && j < ti[k]);
#pragma unroll
        for (int k = KTOP - 1; k >= 1; --k) {
            tv[k] = cc[k] ? (cc[k - 1] ? tv[k - 1] : v) : tv[k];
            ti[k] = cc[k] ? (cc[k - 1] ? ti[k - 1] : j) : ti[k];
        }
        if (cc[0]) { tv[0] = v; ti[0] = j; }
    }
}

// 10 wave-argmax extraction rounds over 64 lane-local ladders; no barriers.
// Lane r (r<10) receives rank-r (value,index). Pop via static shift.
__device__ __forceinline__ void wave_extract10(float (&tv)[KTOP], int (&ti)[KTOP],
                                               int lane, float &myv, int &myi) {
#pragma unroll
    for (int r = 0; r < KTOP; ++r) {
        float bv = tv[0]; int bi = ti[0]; int bl = lane;
#pragma unroll
        for (int m = 32; m >= 1; m >>= 1) {
            const float ov = __shfl_xor(bv, m);
            const int   oi = __shfl_xor(bi, m);
            const int   ol = __shfl_xor(bl, m);
            const bool take = (ov > bv) || (ov == bv && oi < bi);
            bv = take ? ov : bv;
            bi = take ? oi : bi;
            bl = take ? ol : bl;
        }
        if (lane == bl) {                       // winner pops its list head (static shift)
#pragma unroll
            for (int k = 0; k < KTOP - 1; ++k) { tv[k] = tv[k + 1]; ti[k] = ti[k + 1]; }
            tv[KTOP - 1] = -INFINITY; ti[KTOP - 1] = 0x7fffffff;
        }
        if (lane == r) { myv = bv; myi = bi; }
    }
}

// Shared epilogue for one wave owning one row: merge candidates -> loss.
__device__ __forceinline__ void wave_loss(float (&tv)[KTOP], int (&ti)[KTOP], int lane,
                                          const int* __restrict__ mrow, float* __restrict__ dst) {
    float myv = 0.0f; int myi = 0;
    wave_extract10(tv, ti, lane, myv, myi);
    const int pos = (lane < KTOP) ? ((mrow[myi] != 0) ? 1 : 0) : 0;
    int cnt = pos;
#pragma unroll
    for (int m = 32; m >= 1; m >>= 1) cnt += __shfl_xor(cnt, m);
    const float invd = 1.0f / log2f((float)(lane + 2));   // 1/log2(rank+1)
    float a = pos ? invd : 0.0f;
    float b = (lane < cnt) ? invd : 0.0f;
#pragma unroll
    for (int m = 32; m >= 1; m >>= 1) { a += __shfl_xor(a, m); b += __shfl_xor(b, m); }
    if (lane == 0) *dst = (b > 0.0f) ? (1.0f - a / b) : 0.0f;
}

// ---- Kernel A: pure stream + threshold collect (round-3's proven pass-1), dump to global ----
__global__ __launch_bounds__(THREADS) void collect_rows(
    const float* __restrict__ scores,
    float* __restrict__ gval, int* __restrict__ gidx, int* __restrict__ counts)
{
    const int row = blockIdx.x;
    const int tid = threadIdx.x;
    const float4* row4 = reinterpret_cast<const float4*>(scores + (size_t)row * BD);

    __shared__ int   s_cnt;
    __shared__ float cv[CAPL];
    __shared__ int   ci[CAPL];
    if (tid == 0) s_cnt = 0;
    __syncthreads();

    for (int i = 0; i < ITERS; ++i) {          // plain loop: compiler pipelines this well
        const int f4 = tid + i * THREADS;
        const float4 x = row4[f4];
        const float m = fmaxf(fmaxf(x.x, x.y), fmaxf(x.z, x.w));
        if (m >= T_STATIC) {
            const int jb = f4 * 4;
            const float vs[4] = { x.x, x.y, x.z, x.w };
#pragma unroll
            for (int c = 0; c < 4; ++c) {
                if (vs[c] >= T_STATIC) {
                    const int p = atomicAdd(&s_cnt, 1);
                    if (p < CAPL) { cv[p] = vs[c]; ci[p] = jb + c; }
                }
            }
        }
    }
    __syncthreads();
    const int n = s_cnt;
    const int nw = (n < CAPG) ? ((n < CAPL) ? n : CAPL) : CAPG;
    for (int p = tid; p < nw; p += THREADS) {
        gval[(size_t)row * CAPG + p] = cv[p];
        gidx[(size_t)row * CAPG + p] = ci[p];
    }
    if (tid == 0) counts[row] = n;
}

// ---- Kernel B: one wave per row; merge candidates (or exact rescan) -> loss ----
__global__ __launch_bounds__(64) void merge_rows(
    const float* __restrict__ scores, const int* __restrict__ mask,
    const float* __restrict__ gval, const int* __restrict__ gidx,
    const int* __restrict__ counts, float* __restrict__ per_row)
{
    const int row  = blockIdx.x;
    const int lane = threadIdx.x;
    const int n = counts[row];

    float tv[KTOP]; int ti[KTOP];
#pragma unroll
    for (int k = 0; k < KTOP; ++k) { tv[k] = -INFINITY; ti[k] = 0x7fffffff; }

    if (n >= KTOP && n <= CAPG) {
        for (int p = lane; p < n; p += 64)
            insert_tie(gval[(size_t)row * CAPG + p], gidx[(size_t)row * CAPG + p], tv, ti);
    } else {
        // Exact fallback for ANY input: wave rescans the full row (never taken for N(0,1)).
        const float4* row4 = reinterpret_cast<const float4*>(scores + (size_t)row * BD);
        for (int f4 = lane; f4 < F4_PER_ROW; f4 += 64) {
            const float4 x = row4[f4];
            const int jb = f4 * 4;
            const float vs[4] = { x.x, x.y, x.z, x.w };
#pragma unroll
            for (int c = 0; c < 4; ++c) insert_tie(vs[c], jb + c, tv, ti);
        }
    }
    wave_loss(tv, ti, lane, mask + (size_t)row * BD, per_row + row);
}

// ---- Fused fallback (round-3 structure) if ws is too small ----
__global__ __launch_bounds__(THREADS) void topk_ndcg_fused(
    const float* __restrict__ scores, const int* __restrict__ mask,
    float* __restrict__ per_row)
{
    const int row  = blockIdx.x;
    const int tid  = threadIdx.x;
    const int lane = tid & 63;
    const int wv   = tid >> 6;
    const float4* row4 = reinterpret_cast<const float4*>(scores + (size_t)row * BD);

    __shared__ int   s_cnt;
    __shared__ float cv[CAP_FUSED];
    __shared__ int   ci[CAP_FUSED];
    if (tid == 0) s_cnt = 0;
    __syncthreads();

    for (int i = 0; i < ITERS; ++i) {
        const int f4 = tid + i * THREADS;
        const float4 x = row4[f4];
        const float m = fmaxf(fmaxf(x.x, x.y), fmaxf(x.z, x.w));
        if (m >= T_STATIC) {
            const int jb = f4 * 4;
            const float vs[4] = { x.x, x.y, x.z, x.w };
#pragma unroll
            for (int c = 0; c < 4; ++c) {
                if (vs[c] >= T_STATIC) {
                    const int p = atomicAdd(&s_cnt, 1);
                    if (p < CAP_FUSED) { cv[p] = vs[c]; ci[p] = jb + c; }
                }
            }
        }
    }
    __syncthreads();
    int n = s_cnt;

    float tv[KTOP]; int ti[KTOP];
#pragma unroll
    for (int k = 0; k < KTOP; ++k) { tv[k] = -INFINITY; ti[k] = 0x7fffffff; }

    if (n < KTOP || n > CAP_FUSED) {
        for (int i = 0; i < ITERS; ++i) {
            const int f4 = i * THREADS + tid;
            const float4 x = row4[f4];
            const int jb = f4 * 4;
            const float vs[4] = { x.x, x.y, x.z, x.w };
#pragma unroll
            for (int c = 0; c < 4; ++c) insert_tie(vs[c], jb + c, tv, ti);
        }
        float fv = 0.0f; int fi = 0;
        wave_extract10(tv, ti, lane, fv, fi);
        if (lane < KTOP) { cv[wv * KTOP + lane] = fv; ci[wv * KTOP + lane] = fi; }
        __syncthreads();
        n = 4 * KTOP;
#pragma unroll
        for (int k = 0; k < KTOP; ++k) { tv[k] = -INFINITY; ti[k] = 0x7fffffff; }
    }

    if (wv == 0) {
        for (int p = lane; p < n; p += 64) insert_tie(cv[p], ci[p], tv, ti);
        wave_loss(tv, ti, lane, mask + (size_t)row * BD, per_row + row);
    }
}

// Deterministic reduction of the 4096 per-row losses -> scalar mean.
__global__ __launch_bounds__(256) void reduce_mean(
    const float* __restrict__ per_row, float* __restrict__ out)
{
    const int tid = threadIdx.x;
    float s = 0.0f;
    for (int i = tid; i < BQ; i += 256) s += per_row[i];
#pragma unroll
    for (int m = 32; m >= 1; m >>= 1) s += __shfl_xor(s, m);
    __shared__ float ws[4];
    if ((tid & 63) == 0) ws[tid >> 6] = s;
    __syncthreads();
    if (tid == 0) out[0] = (ws[0] + ws[1] + ws[2] + ws[3]) / (float)BQ;
}

extern "C" void kernel_launch(void* const* d_in, const int* in_sizes, int n_in,
                              void* d_out, int out_size, void* d_ws, size_t ws_size,
                              hipStream_t stream) {
    const float* scores = (const float*)d_in[0];
    const int*   mask   = (const int*)d_in[1];     // bool_ -> int32 on device

    char* ws = (char*)d_ws;
    float* per_row = (float*)ws;                   // 16 KB
    int*   counts  = (int*)(ws + 32768 - 16384);   // 16 KB at offset 16KB
    float* gval    = (float*)(ws + 32768);
    int*   gidx    = (int*)(ws + 32768 + (size_t)BQ * CAPG * 4);

    if (ws_size >= WS_REQ) {
        collect_rows<<<BQ, THREADS, 0, stream>>>(scores, gval, gidx, counts);
        merge_rows<<<BQ, 64, 0, stream>>>(scores, mask, gval, gidx, counts, per_row);
    } else {
        topk_ndcg_fused<<<BQ, THREADS, 0, stream>>>(scores, mask, per_row);
    }
    reduce_mean<<<1, 256, 0, stream>>>(per_row, (float*)d_out);
}